// Round 14
// baseline (62.572 us; speedup 1.0000x reference)
//
#include <hip/hip_runtime.h>

#define DI __device__ __forceinline__

typedef __bf16 bf16x8 __attribute__((ext_vector_type(8)));
typedef float  f32x4  __attribute__((ext_vector_type(4)));
typedef unsigned short u16;
typedef unsigned int   u32;

constexpr int BATCH  = 2;
constexpr int NNODE  = 4097;          // 64*64 grid + 1 global token
constexpr int M_REAL = BATCH * NNODE; // 8194
constexpr int M_PAD  = 8448;          // padded rows in Xp/QKV buffers
constexpr int KDIM   = 512;

// dense global-token row: split-K softmax partials
constexpr int JC     = 256;                        // keys per chunk
constexpr int NCHUNK = (NNODE + JC - 1) / JC;      // 17
constexpr int NDB    = BATCH * 8 * NCHUNK;         // 272 dense phase-A blocks

DI float bf2f(u16 u)  { return __uint_as_float(((u32)u) << 16); }
DI float bflo(u32 v)  { return __uint_as_float(v << 16); }
DI float bfhi(u32 v)  { return __uint_as_float(v & 0xffff0000u); }
DI u16   f2bf(float f) {
  u32 u = __float_as_uint(f);
  u32 r = (u + 0x7fffu + ((u >> 16) & 1u)) >> 16;   // RNE
  return (u16)r;
}

DI void gload_lds16(const void* g, void* l) {
  __builtin_amdgcn_global_load_lds(
      (const __attribute__((address_space(1))) u32*)g,
      (__attribute__((address_space(3))) u32*)l, 16, 0, 0);
}

// ---------------------------------------------------------------- prep ----
constexpr int NCH_X  = M_PAD * KDIM / 8;   // 540672
constexpr int NCH_WQ = 1536 * KDIM / 8;    // 98304
constexpr int NCH_WO = 512 * KDIM / 8;     // 32768

__global__ __launch_bounds__(256) void prep(
    const float* __restrict__ x,  const float* __restrict__ wq,
    const float* __restrict__ wk, const float* __restrict__ wv,
    const float* __restrict__ wo,
    u16* __restrict__ Xp, u16* __restrict__ Wqkv, u16* __restrict__ Wob) {
  int idx = blockIdx.x * 256 + threadIdx.x;
  const float* src = nullptr;
  u16* dst = nullptr;
  bool zero = false;
  if (idx < NCH_X) {
    int row = idx >> 6;
    dst = Xp + (size_t)idx * 8;
    if (row < M_REAL) src = x + (size_t)idx * 8; else zero = true;
  } else if (idx < NCH_X + NCH_WQ) {
    int t = idx - NCH_X;
    int row = t >> 6;
    dst = Wqkv + (size_t)t * 8;
    const float* W = row < 512 ? wq : (row < 1024 ? wk : wv);
    src = W + ((size_t)(row & 511) << 9) + ((t & 63) * 8);
  } else if (idx < NCH_X + NCH_WQ + NCH_WO) {
    int t = idx - NCH_X - NCH_WQ;
    dst = Wob + (size_t)t * 8;
    src = wo + (size_t)t * 8;
  } else {
    return;
  }
  u32 o[4];
  if (zero) {
    o[0] = o[1] = o[2] = o[3] = 0u;
  } else {
    float4 f0 = ((const float4*)src)[0];
    float4 f1 = ((const float4*)src)[1];
    o[0] = (u32)f2bf(f0.x) | ((u32)f2bf(f0.y) << 16);
    o[1] = (u32)f2bf(f0.z) | ((u32)f2bf(f0.w) << 16);
    o[2] = (u32)f2bf(f1.x) | ((u32)f2bf(f1.y) << 16);
    o[3] = (u32)f2bf(f1.z) | ((u32)f2bf(f1.w) << 16);
  }
  uint4 v; v.x = o[0]; v.y = o[1]; v.z = o[2]; v.w = o[3];
  *(uint4*)dst = v;
}

// ------------------------------------------------- 224x256 dbuf GEMM ------
// (unchanged from R12 — 222 blocks one-round, staged-bytes audited)
__global__ __launch_bounds__(512, 2) void gemm224(
    const u16* __restrict__ A, const u16* __restrict__ B,
    u16* __restrict__ C) {
  __shared__ __align__(16) u16 SM[61440];  // A bytes [0,57344), B [57344,122880)
  const int tid  = threadIdx.x;
  const int lane = tid & 63;
  const int wid  = tid >> 6;
  const int wm   = wid >> 2;   // 0..1
  const int wn   = wid & 3;    // 0..3

  const int obid = blockIdx.x;            // 0..221; 222 = 8*27+6
  const int xcd = obid & 7, loc = obid >> 3;
  const int wgid = (xcd < 6) ? xcd * 28 + loc : 168 + (xcd - 6) * 27 + loc;
  const int m0 = (wgid / 6) * 224;
  const int n0 = (wgid % 6) * 256;

  const int l15 = lane & 15, l7 = lane & 7, lg = lane >> 4;

  const u16* AgP[4];
#pragma unroll
  for (int i = 0; i < 3; ++i) {
    const int s = tid + 512 * i;
    const int row = s >> 3, g = s & 7;
    AgP[i] = A + (size_t)(m0 + row) * KDIM + ((g ^ (row & 7)) << 3);
  }
  {
    const int s = 1536 + (tid & 255);        // used only by tid < 256
    const int row = s >> 3, g = s & 7;
    AgP[3] = A + (size_t)(m0 + row) * KDIM + ((g ^ (row & 7)) << 3);
  }
  const u16* BgP[4];
#pragma unroll
  for (int i = 0; i < 4; ++i) {
    const int s = tid + 512 * i;
    const int row = s >> 3, g = s & 7;
    BgP[i] = B + (size_t)(n0 + row) * KDIM + ((g ^ (row & 7)) << 3);
  }

  const int kx0 = ((lg * 8)       ^ (l7 << 3));
  const int kx1 = (((4 | lg) * 8) ^ (l7 << 3));
  const int aBase = wm * 7168 + l15 * 64;             // elems (112 rows/wave)
  const int bBase = 28672 + wn * 4096 + l15 * 64;     // B region at elem 28672

  f32x4 acc[7][4] = {};
  constexpr int NT = KDIM / 64;   // 8

  auto stage = [&](int t, int buf) {
#pragma unroll
    for (int i = 0; i < 3; ++i)
      gload_lds16(AgP[i] + t * 64,
                  (char*)SM + buf * 28672 + (tid + 512 * i) * 16);
    if (tid < 256)
      gload_lds16(AgP[3] + t * 64,
                  (char*)SM + buf * 28672 + (1536 + tid) * 16);
#pragma unroll
    for (int i = 0; i < 4; ++i)
      gload_lds16(BgP[i] + t * 64,
                  (char*)SM + 57344 + buf * 32768 + (tid + 512 * i) * 16);
  };

  stage(0, 0);

  for (int t = 0; t < NT; ++t) {
    const int buf = t & 1;
    if (t + 1 < NT) {
      stage(t + 1, buf ^ 1);
      if (tid < 256) asm volatile("s_waitcnt vmcnt(8)" ::: "memory");
      else           asm volatile("s_waitcnt vmcnt(7)" ::: "memory");
    } else {
      asm volatile("s_waitcnt vmcnt(0)" ::: "memory");
    }
    asm volatile("s_barrier" ::: "memory");  // all waves: tile t resident

    const int aB = aBase + buf * 14336;   // elems
    const int bB = bBase + buf * 16384;

    bf16x8 bfr[4][2];
#pragma unroll
    for (int ni = 0; ni < 4; ++ni) {
      bfr[ni][0] = *(const bf16x8*)&SM[bB + ni * 1024 + kx0];
      bfr[ni][1] = *(const bf16x8*)&SM[bB + ni * 1024 + kx1];
    }
    {
      bf16x8 af[4][2];
#pragma unroll
      for (int i = 0; i < 4; ++i) {
        af[i][0] = *(const bf16x8*)&SM[aB + i * 1024 + kx0];
        af[i][1] = *(const bf16x8*)&SM[aB + i * 1024 + kx1];
      }
      __builtin_amdgcn_s_setprio(1);
#pragma unroll
      for (int i = 0; i < 4; ++i)
#pragma unroll
        for (int ni = 0; ni < 4; ++ni) {
          acc[i][ni] = __builtin_amdgcn_mfma_f32_16x16x32_bf16(
              af[i][0], bfr[ni][0], acc[i][ni], 0, 0, 0);
          acc[i][ni] = __builtin_amdgcn_mfma_f32_16x16x32_bf16(
              af[i][1], bfr[ni][1], acc[i][ni], 0, 0, 0);
        }
      __builtin_amdgcn_s_setprio(0);
    }
    {
      bf16x8 af[3][2];
#pragma unroll
      for (int i = 0; i < 3; ++i) {
        af[i][0] = *(const bf16x8*)&SM[aB + (4 + i) * 1024 + kx0];
        af[i][1] = *(const bf16x8*)&SM[aB + (4 + i) * 1024 + kx1];
      }
      __builtin_amdgcn_s_setprio(1);
#pragma unroll
      for (int i = 0; i < 3; ++i)
#pragma unroll
        for (int ni = 0; ni < 4; ++ni) {
          acc[4+i][ni] = __builtin_amdgcn_mfma_f32_16x16x32_bf16(
              af[i][0], bfr[ni][0], acc[4+i][ni], 0, 0, 0);
          acc[4+i][ni] = __builtin_amdgcn_mfma_f32_16x16x32_bf16(
              af[i][1], bfr[ni][1], acc[4+i][ni], 0, 0, 0);
        }
      __builtin_amdgcn_s_setprio(0);
    }
    asm volatile("s_barrier" ::: "memory");  // reads done before buf reuse
  }

  const int cr = lg * 4, cc = l15;
#pragma unroll
  for (int mi = 0; mi < 7; ++mi)
#pragma unroll
    for (int j = 0; j < 4; ++j) {
      const int row = m0 + wm * 112 + mi * 16 + cr + j;  // < 8288 <= M_PAD
#pragma unroll
      for (int ni = 0; ni < 4; ++ni) {
        const int col = n0 + wn * 64 + ni * 16 + cc;
        C[(size_t)row * 1536 + col] = f2bf(acc[mi][ni][j]);
      }
    }
}

// --------------- 160x128 dbuf GEMM + 2 DEDICATED fin-blocks ---------------
// Grid 210 (<= 256 CUs, still one round). Blocks 0..207: GEMM (R12 form,
// epilogue skips dense rows 0/4097). Blocks 208/209: dense-row finisher —
// merge Part per (b,h) and write out rows 0/4097 as f32 dot merged·Wob^T,
// CONCURRENT with the GEMM blocks (hidden under their ~4.5us makespan).
// R13 lesson: appending tail work to one-round-grid members extends the
// makespan; dedicating idle CUs hides it. No sync/atomics; writes disjoint
// (GEMM skips rows 0/4097; ATT rows 0/4097 never written -> finite 0xAA
// garbage feeds discarded accs only).
__global__ __launch_bounds__(256, 1) void gemm160(
    const u16* __restrict__ A, const u16* __restrict__ B,
    float* __restrict__ Cf, const float* __restrict__ Part) {
  __shared__ __align__(16) u16 SM[36864];
  const int tid  = threadIdx.x;

  if (blockIdx.x >= 208) {
    // ---- dedicated dense-row finisher (bb = 0 -> row 0, bb = 1 -> row 4097)
    const int bb = blockIdx.x - 208;
    const size_t rowfix = (size_t)bb * NNODE;
    float* mg = (float*)SM;   // 512 floats
    {
      const int h = tid >> 5;
      const int d0 = (tid & 31) * 2;
      const float* P = Part + (size_t)(bb * 8 + h) * NCHUNK * 66;
      float m = -3e38f;
#pragma unroll
      for (int c2 = 0; c2 < NCHUNK; ++c2) m = fmaxf(m, P[c2 * 66]);
      float ssm = 0.f, o0 = 0.f, o1 = 0.f;
#pragma unroll
      for (int c2 = 0; c2 < NCHUNK; ++c2) {
        const float ex = __expf(P[c2 * 66] - m);
        ssm += P[c2 * 66 + 1] * ex;
        o0  += P[c2 * 66 + 2 + d0] * ex;
        o1  += P[c2 * 66 + 2 + d0 + 1] * ex;
      }
      mg[h * 64 + d0]     = bf2f(f2bf(o0 / ssm));  // match bf16 ATT rounding
      mg[h * 64 + d0 + 1] = bf2f(f2bf(o1 / ssm));
    }
    __syncthreads();
#pragma unroll
    for (int cc2 = 0; cc2 < 2; ++cc2) {
      const int col = tid * 2 + cc2;
      const u16* wrow = B + (size_t)col * KDIM;   // Wob row-major [512][512]
      float a2 = 0.f;
#pragma unroll 4
      for (int k = 0; k < KDIM; k += 8) {
        const uint4 wv = *(const uint4*)(wrow + k);
        a2 += mg[k+0]*bflo(wv.x) + mg[k+1]*bfhi(wv.x)
            + mg[k+2]*bflo(wv.y) + mg[k+3]*bfhi(wv.y)
            + mg[k+4]*bflo(wv.z) + mg[k+5]*bfhi(wv.z)
            + mg[k+6]*bflo(wv.w) + mg[k+7]*bfhi(wv.w);
      }
      Cf[rowfix * 512 + col] = a2;
    }
    return;
  }

  // ---- GEMM blocks (R12 form) ----
  const int lane = tid & 63;
  const int wid  = tid >> 6;      // 0..3
  const int wm   = wid >> 1, wn = wid & 1;

  const int obid = blockIdx.x;            // 0..207, 208 % 8 == 0
  const int wgid = (obid & 7) * 26 + (obid >> 3);
  const int m0 = (wgid >> 2) * 160;
  const int n0 = (wgid & 3) * 128;

  const int l15 = lane & 15, l7 = lane & 7, lg = lane >> 4;

  const u16* AgP[5];
#pragma unroll
  for (int i = 0; i < 5; ++i) {
    const int s = tid + 256 * i;
    const int row = s >> 3, g = s & 7;
    AgP[i] = A + (size_t)(m0 + row) * KDIM + ((g ^ (row & 7)) << 3);
  }
  const u16* BgP[4];
#pragma unroll
  for (int i = 0; i < 4; ++i) {
    const int s = tid + 256 * i;
    const int row = s >> 3, g = s & 7;
    BgP[i] = B + (size_t)(n0 + row) * KDIM + ((g ^ (row & 7)) << 3);
  }

  const int kx0 = ((lg * 8)       ^ (l7 << 3));
  const int kx1 = (((4 | lg) * 8) ^ (l7 << 3));
  const int aBase = wm * 5120 + l15 * 64;
  const int bBase = 20480 + wn * 4096 + l15 * 64;

  f32x4 acc[5][4] = {};
  constexpr int NT = KDIM / 64;   // 8

  auto stage = [&](int t, int buf) {
#pragma unroll
    for (int i = 0; i < 5; ++i)
      gload_lds16(AgP[i] + t * 64,
                  (char*)SM + buf * 20480 + (tid + 256 * i) * 16);
#pragma unroll
    for (int i = 0; i < 4; ++i)
      gload_lds16(BgP[i] + t * 64,
                  (char*)SM + 40960 + buf * 16384 + (tid + 256 * i) * 16);
  };

  stage(0, 0);

  for (int t = 0; t < NT; ++t) {
    const int buf = t & 1;
    if (t + 1 < NT) {
      stage(t + 1, buf ^ 1);
      asm volatile("s_waitcnt vmcnt(9)" ::: "memory");
    } else {
      asm volatile("s_waitcnt vmcnt(0)" ::: "memory");
    }
    asm volatile("s_barrier" ::: "memory");

    const int aB = aBase + buf * 10240;
    const int bB = bBase + buf * 8192;

    bf16x8 bfr[4][2];
#pragma unroll
    for (int ni = 0; ni < 4; ++ni) {
      bfr[ni][0] = *(const bf16x8*)&SM[bB + ni * 1024 + kx0];
      bfr[ni][1] = *(const bf16x8*)&SM[bB + ni * 1024 + kx1];
    }
    bf16x8 af[5][2];
#pragma unroll
    for (int i = 0; i < 5; ++i) {
      af[i][0] = *(const bf16x8*)&SM[aB + i * 1024 + kx0];
      af[i][1] = *(const bf16x8*)&SM[aB + i * 1024 + kx1];
    }
    __builtin_amdgcn_s_setprio(1);
#pragma unroll
    for (int i = 0; i < 5; ++i)
#pragma unroll
      for (int ni = 0; ni < 4; ++ni) {
        acc[i][ni] = __builtin_amdgcn_mfma_f32_16x16x32_bf16(
            af[i][0], bfr[ni][0], acc[i][ni], 0, 0, 0);
        acc[i][ni] = __builtin_amdgcn_mfma_f32_16x16x32_bf16(
            af[i][1], bfr[ni][1], acc[i][ni], 0, 0, 0);
      }
    __builtin_amdgcn_s_setprio(0);
    asm volatile("s_barrier" ::: "memory");
  }

  const int cr = lg * 4, cc = l15;
#pragma unroll
  for (int mi = 0; mi < 5; ++mi)
#pragma unroll
    for (int j = 0; j < 4; ++j) {
      const int row = m0 + wm * 80 + mi * 16 + cr + j;
      if (row >= M_REAL) continue;
      if (row == 0 || row == NNODE) continue;   // dense rows: fin-blocks own them
#pragma unroll
      for (int ni = 0; ni < 4; ++ni) {
        const int col = n0 + wn * 64 + ni * 16 + cc;
        Cf[(size_t)row * 512 + col] = acc[mi][ni][j];
      }
    }
}

// ------------------------------------------------------------ attention ----
// (unchanged from R12) blocks [0,NDB): dense-row phase A; [NDB,..): sparse.
__global__ __launch_bounds__(256) void attn(const u16* __restrict__ QKV,
                                            u16* __restrict__ O,
                                            float* __restrict__ Part) {
  const int tid = threadIdx.x;
  if (blockIdx.x < NDB) {
    __shared__ float qs[64];
    __shared__ float ev[JC];
    __shared__ float red[256];
    const int db = blockIdx.x;
    const int b  = db / (8 * NCHUNK);
    const int rm = db % (8 * NCHUNK);
    const int h  = rm / NCHUNK;
    const int ch = rm % NCHUNK;
    const int j0 = ch * JC;
    const size_t base = (size_t)b * NNODE;

    if (tid < 64) qs[tid] = bf2f(QKV[base * 1536 + h * 64 + tid]);
    __syncthreads();

    const int j = j0 + tid;
    float s = -3e38f;
    if (j < NNODE) {
      const uint4* kp4 = (const uint4*)(QKV + (base + j) * 1536 + 512 + h * 64);
      float a = 0.f;
#pragma unroll
      for (int q8 = 0; q8 < 8; ++q8) {
        uint4 kv = kp4[q8];
        int d = q8 * 8;
        a += qs[d+0]*bflo(kv.x) + qs[d+1]*bfhi(kv.x)
           + qs[d+2]*bflo(kv.y) + qs[d+3]*bfhi(kv.y)
           + qs[d+4]*bflo(kv.z) + qs[d+5]*bfhi(kv.z)
           + qs[d+6]*bflo(kv.w) + qs[d+7]*bfhi(kv.w);
      }
      s = a * 0.125f;
    }
    red[tid] = s;
    __syncthreads();
    for (int st = 128; st > 0; st >>= 1) {
      if (tid < st) red[tid] = fmaxf(red[tid], red[tid + st]);
      __syncthreads();
    }
    const float mx = red[0];
    __syncthreads();
    const float e = (j < NNODE) ? __expf(s - mx) : 0.f;
    ev[tid] = e;
    red[tid] = e;
    __syncthreads();
    for (int st = 128; st > 0; st >>= 1) {
      if (tid < st) red[tid] += red[tid + st];
      __syncthreads();
    }
    const float ssum = red[0];
    __syncthreads();

    const int w = tid >> 6, lane = tid & 63;
    const int js = lane >> 3, dg = lane & 7;
    float oa[8] = {};
#pragma unroll
    for (int jj = 0; jj < 8; ++jj) {
      const int li = w * 64 + jj * 8 + js;
      const int jv = j0 + li;
      if (jv < NNODE) {
        const float we = ev[li];
        const uint4 vv = *(const uint4*)(QKV + (base + jv) * 1536 + 1024 + h * 64 + dg * 8);
        oa[0] += we * bflo(vv.x); oa[1] += we * bfhi(vv.x);
        oa[2] += we * bflo(vv.y); oa[3] += we * bfhi(vv.y);
        oa[4] += we * bflo(vv.z); oa[5] += we * bfhi(vv.z);
        oa[6] += we * bflo(vv.w); oa[7] += we * bfhi(vv.w);
      }
    }
#pragma unroll
    for (int m = 8; m <= 32; m <<= 1)
#pragma unroll
      for (int t = 0; t < 8; ++t) oa[t] += __shfl_xor(oa[t], m);
    __syncthreads();
    if (lane < 8) {
#pragma unroll
      for (int t = 0; t < 8; ++t) red[w * 64 + lane * 8 + t] = oa[t];
    }
    __syncthreads();
    float* P = Part + ((size_t)((b * 8 + h) * NCHUNK + ch)) * 66;
    if (tid == 0) { P[0] = mx; P[1] = ssum; }
    if (tid < 64)
      P[2 + tid] = red[tid] + red[64 + tid] + red[128 + tid] + red[192 + tid];
    return;
  }

  // ---- sparse rows ----
  const int obid = blockIdx.x - NDB;                    // 0..2047
  const int sb   = ((obid & 7) << 8) | (obid >> 3);     // bijective (2048 % 8 == 0)
  const int wid  = sb * 4 + (tid >> 6);                 // 0..8191
  const int lane = tid & 63;
  const int b = wid >> 12;
  const int g = wid & 4095;
  const int i = g + 1;
  const int r = g >> 6, c = g & 63;
  const size_t base = (size_t)b * NNODE;

  int  jn[6];
  bool vd[6];
  jn[0] = 0;                     vd[0] = true;
  jn[1] = i;                     vd[1] = true;
  jn[2] = (c > 0)  ? i - 1  : i; vd[2] = (c > 0);
  jn[3] = (c < 63) ? i + 1  : i; vd[3] = (c < 63);
  jn[4] = (r > 0)  ? i - 64 : i; vd[4] = (r > 0);
  jn[5] = (r < 63) ? i + 64 : i; vd[5] = (r < 63);

  const uint4 qv = *(const uint4*)(QKV + (base + i) * 1536 + lane * 8);
  float qf[8] = { bflo(qv.x), bfhi(qv.x), bflo(qv.y), bfhi(qv.y),
                  bflo(qv.z), bfhi(qv.z), bflo(qv.w), bfhi(qv.w) };

  float sc[6];
#pragma unroll
  for (int n = 0; n < 6; ++n) {
    const uint4 kv = *(const uint4*)(QKV + (base + jn[n]) * 1536 + 512 + lane * 8);
    float p = qf[0]*bflo(kv.x) + qf[1]*bfhi(kv.x)
            + qf[2]*bflo(kv.y) + qf[3]*bfhi(kv.y)
            + qf[4]*bflo(kv.z) + qf[5]*bfhi(kv.z)
            + qf[6]*bflo(kv.w) + qf[7]*bfhi(kv.w);
    p += __shfl_xor(p, 1);
    p += __shfl_xor(p, 2);
    p += __shfl_xor(p, 4);
    sc[n] = p * 0.125f;
  }
  float mx = -1e30f;
#pragma unroll
  for (int n = 0; n < 6; ++n) if (vd[n]) mx = fmaxf(mx, sc[n]);
  float pw[6], den = 0.f;
#pragma unroll
  for (int n = 0; n < 6; ++n) {
    pw[n] = vd[n] ? __expf(sc[n] - mx) : 0.f;
    den += pw[n];
  }
  const float inv = 1.f / den;

  float oa[8] = {};
#pragma unroll
  for (int n = 0; n < 6; ++n) {
    const uint4 vv = *(const uint4*)(QKV + (base + jn[n]) * 1536 + 1024 + lane * 8);
    const float w = pw[n];
    oa[0] += w * bflo(vv.x); oa[1] += w * bfhi(vv.x);
    oa[2] += w * bflo(vv.y); oa[3] += w * bfhi(vv.y);
    oa[4] += w * bflo(vv.z); oa[5] += w * bfhi(vv.z);
    oa[6] += w * bflo(vv.w); oa[7] += w * bfhi(vv.w);
  }
  uint4 ov;
  ov.x = (u32)f2bf(oa[0] * inv) | ((u32)f2bf(oa[1] * inv) << 16);
  ov.y = (u32)f2bf(oa[2] * inv) | ((u32)f2bf(oa[3] * inv) << 16);
  ov.z = (u32)f2bf(oa[4] * inv) | ((u32)f2bf(oa[5] * inv) << 16);
  ov.w = (u32)f2bf(oa[6] * inv) | ((u32)f2bf(oa[7] * inv) << 16);
  *(uint4*)(O + (base + i) * 512 + lane * 8) = ov;
}

// -------------------------------------------------------------- launch ----
extern "C" void kernel_launch(void* const* d_in, const int* in_sizes, int n_in,
                              void* d_out, int out_size, void* d_ws, size_t ws_size,
                              hipStream_t stream) {
  (void)in_sizes; (void)n_in; (void)out_size; (void)ws_size;
  const float* x  = (const float*)d_in[0];
  const float* wq = (const float*)d_in[1];
  const float* wk = (const float*)d_in[2];
  const float* wv = (const float*)d_in[3];
  const float* wo = (const float*)d_in[4];
  float* out = (float*)d_out;

  char* ws = (char*)d_ws;
  u16* Xp   = (u16*)ws;  ws += (size_t)M_PAD * 512 * 2;   //  8,650,752 B
  u16* Wqkv = (u16*)ws;  ws += (size_t)1536 * 512 * 2;    //  1,572,864 B
  u16* Wob  = (u16*)ws;  ws += (size_t)512 * 512 * 2;     //    524,288 B
  u16* QKV  = (u16*)ws;  ws += (size_t)M_PAD * 1536 * 2;  // 25,952,256 B
  u16* ATT  = (u16*)ws;                                   //  8,650,752 B
  float* Part = (float*)Xp;  // dead after gemm1; 272*66*4 = 72 KB

  prep<<<(NCH_X + NCH_WQ + NCH_WO) / 256, 256, 0, stream>>>(
      x, wq, wk, wv, wo, Xp, Wqkv, Wob);

  gemm224<<<222, 512, 0, stream>>>(Xp, Wqkv, QKV);

  attn<<<NDB + 2048, 256, 0, stream>>>(QKV, ATT, Part);

  gemm160<<<210, 256, 0, stream>>>(ATT, Wob, out, Part);
}

// Round 15
// 55.887 us; speedup vs baseline: 1.1196x; 1.1196x over previous
//
#include <hip/hip_runtime.h>

#define DI __device__ __forceinline__

typedef __bf16 bf16x8 __attribute__((ext_vector_type(8)));
typedef float  f32x4  __attribute__((ext_vector_type(4)));
typedef unsigned short u16;
typedef unsigned int   u32;

constexpr int BATCH  = 2;
constexpr int NNODE  = 4097;          // 64*64 grid + 1 global token
constexpr int M_REAL = BATCH * NNODE; // 8194
constexpr int M_PAD  = 8448;          // padded rows in Xp/QKV buffers
constexpr int KDIM   = 512;

// dense global-token row: split-K softmax partials
constexpr int JC     = 256;                        // keys per chunk
constexpr int NCHUNK = (NNODE + JC - 1) / JC;      // 17
constexpr int NDB    = BATCH * 8 * NCHUNK;         // 272 dense phase-A blocks

DI float bf2f(u16 u)  { return __uint_as_float(((u32)u) << 16); }
DI float bflo(u32 v)  { return __uint_as_float(v << 16); }
DI float bfhi(u32 v)  { return __uint_as_float(v & 0xffff0000u); }
DI u16   f2bf(float f) {
  u32 u = __float_as_uint(f);
  u32 r = (u + 0x7fffu + ((u >> 16) & 1u)) >> 16;   // RNE
  return (u16)r;
}

DI void gload_lds16(const void* g, void* l) {
  __builtin_amdgcn_global_load_lds(
      (const __attribute__((address_space(1))) u32*)g,
      (__attribute__((address_space(3))) u32*)l, 16, 0, 0);
}

// ---------------------------------------------------------------- prep ----
constexpr int NCH_X  = M_PAD * KDIM / 8;   // 540672
constexpr int NCH_WQ = 1536 * KDIM / 8;    // 98304
constexpr int NCH_WO = 512 * KDIM / 8;     // 32768

__global__ __launch_bounds__(256) void prep(
    const float* __restrict__ x,  const float* __restrict__ wq,
    const float* __restrict__ wk, const float* __restrict__ wv,
    const float* __restrict__ wo,
    u16* __restrict__ Xp, u16* __restrict__ Wqkv, u16* __restrict__ Wob) {
  int idx = blockIdx.x * 256 + threadIdx.x;
  const float* src = nullptr;
  u16* dst = nullptr;
  bool zero = false;
  if (idx < NCH_X) {
    int row = idx >> 6;
    dst = Xp + (size_t)idx * 8;
    if (row < M_REAL) src = x + (size_t)idx * 8; else zero = true;
  } else if (idx < NCH_X + NCH_WQ) {
    int t = idx - NCH_X;
    int row = t >> 6;
    dst = Wqkv + (size_t)t * 8;
    const float* W = row < 512 ? wq : (row < 1024 ? wk : wv);
    src = W + ((size_t)(row & 511) << 9) + ((t & 63) * 8);
  } else if (idx < NCH_X + NCH_WQ + NCH_WO) {
    int t = idx - NCH_X - NCH_WQ;
    dst = Wob + (size_t)t * 8;
    src = wo + (size_t)t * 8;
  } else {
    return;
  }
  u32 o[4];
  if (zero) {
    o[0] = o[1] = o[2] = o[3] = 0u;
  } else {
    float4 f0 = ((const float4*)src)[0];
    float4 f1 = ((const float4*)src)[1];
    o[0] = (u32)f2bf(f0.x) | ((u32)f2bf(f0.y) << 16);
    o[1] = (u32)f2bf(f0.z) | ((u32)f2bf(f0.w) << 16);
    o[2] = (u32)f2bf(f1.x) | ((u32)f2bf(f1.y) << 16);
    o[3] = (u32)f2bf(f1.z) | ((u32)f2bf(f1.w) << 16);
  }
  uint4 v; v.x = o[0]; v.y = o[1]; v.z = o[2]; v.w = o[3];
  *(uint4*)dst = v;
}

// ------------------------------------------------- 224x256 dbuf GEMM ------
// 222 blocks one-round; staged-bytes audited (A 28672 B, B 32768 B / buf).
__global__ __launch_bounds__(512, 2) void gemm224(
    const u16* __restrict__ A, const u16* __restrict__ B,
    u16* __restrict__ C) {
  __shared__ __align__(16) u16 SM[61440];  // A bytes [0,57344), B [57344,122880)
  const int tid  = threadIdx.x;
  const int lane = tid & 63;
  const int wid  = tid >> 6;
  const int wm   = wid >> 2;   // 0..1
  const int wn   = wid & 3;    // 0..3

  const int obid = blockIdx.x;            // 0..221; 222 = 8*27+6
  const int xcd = obid & 7, loc = obid >> 3;
  const int wgid = (xcd < 6) ? xcd * 28 + loc : 168 + (xcd - 6) * 27 + loc;
  const int m0 = (wgid / 6) * 224;
  const int n0 = (wgid % 6) * 256;

  const int l15 = lane & 15, l7 = lane & 7, lg = lane >> 4;

  const u16* AgP[4];
#pragma unroll
  for (int i = 0; i < 3; ++i) {
    const int s = tid + 512 * i;
    const int row = s >> 3, g = s & 7;
    AgP[i] = A + (size_t)(m0 + row) * KDIM + ((g ^ (row & 7)) << 3);
  }
  {
    const int s = 1536 + (tid & 255);        // used only by tid < 256
    const int row = s >> 3, g = s & 7;
    AgP[3] = A + (size_t)(m0 + row) * KDIM + ((g ^ (row & 7)) << 3);
  }
  const u16* BgP[4];
#pragma unroll
  for (int i = 0; i < 4; ++i) {
    const int s = tid + 512 * i;
    const int row = s >> 3, g = s & 7;
    BgP[i] = B + (size_t)(n0 + row) * KDIM + ((g ^ (row & 7)) << 3);
  }

  const int kx0 = ((lg * 8)       ^ (l7 << 3));
  const int kx1 = (((4 | lg) * 8) ^ (l7 << 3));
  const int aBase = wm * 7168 + l15 * 64;             // elems (112 rows/wave)
  const int bBase = 28672 + wn * 4096 + l15 * 64;     // B region at elem 28672

  f32x4 acc[7][4] = {};
  constexpr int NT = KDIM / 64;   // 8

  auto stage = [&](int t, int buf) {
#pragma unroll
    for (int i = 0; i < 3; ++i)
      gload_lds16(AgP[i] + t * 64,
                  (char*)SM + buf * 28672 + (tid + 512 * i) * 16);
    if (tid < 256)
      gload_lds16(AgP[3] + t * 64,
                  (char*)SM + buf * 28672 + (1536 + tid) * 16);
#pragma unroll
    for (int i = 0; i < 4; ++i)
      gload_lds16(BgP[i] + t * 64,
                  (char*)SM + 57344 + buf * 32768 + (tid + 512 * i) * 16);
  };

  stage(0, 0);

  for (int t = 0; t < NT; ++t) {
    const int buf = t & 1;
    if (t + 1 < NT) {
      stage(t + 1, buf ^ 1);
      if (tid < 256) asm volatile("s_waitcnt vmcnt(8)" ::: "memory");
      else           asm volatile("s_waitcnt vmcnt(7)" ::: "memory");
    } else {
      asm volatile("s_waitcnt vmcnt(0)" ::: "memory");
    }
    asm volatile("s_barrier" ::: "memory");  // all waves: tile t resident

    const int aB = aBase + buf * 14336;   // elems
    const int bB = bBase + buf * 16384;

    bf16x8 bfr[4][2];
#pragma unroll
    for (int ni = 0; ni < 4; ++ni) {
      bfr[ni][0] = *(const bf16x8*)&SM[bB + ni * 1024 + kx0];
      bfr[ni][1] = *(const bf16x8*)&SM[bB + ni * 1024 + kx1];
    }
    {
      bf16x8 af[4][2];
#pragma unroll
      for (int i = 0; i < 4; ++i) {
        af[i][0] = *(const bf16x8*)&SM[aB + i * 1024 + kx0];
        af[i][1] = *(const bf16x8*)&SM[aB + i * 1024 + kx1];
      }
      __builtin_amdgcn_s_setprio(1);
#pragma unroll
      for (int i = 0; i < 4; ++i)
#pragma unroll
        for (int ni = 0; ni < 4; ++ni) {
          acc[i][ni] = __builtin_amdgcn_mfma_f32_16x16x32_bf16(
              af[i][0], bfr[ni][0], acc[i][ni], 0, 0, 0);
          acc[i][ni] = __builtin_amdgcn_mfma_f32_16x16x32_bf16(
              af[i][1], bfr[ni][1], acc[i][ni], 0, 0, 0);
        }
      __builtin_amdgcn_s_setprio(0);
    }
    {
      bf16x8 af[3][2];
#pragma unroll
      for (int i = 0; i < 3; ++i) {
        af[i][0] = *(const bf16x8*)&SM[aB + (4 + i) * 1024 + kx0];
        af[i][1] = *(const bf16x8*)&SM[aB + (4 + i) * 1024 + kx1];
      }
      __builtin_amdgcn_s_setprio(1);
#pragma unroll
      for (int i = 0; i < 3; ++i)
#pragma unroll
        for (int ni = 0; ni < 4; ++ni) {
          acc[4+i][ni] = __builtin_amdgcn_mfma_f32_16x16x32_bf16(
              af[i][0], bfr[ni][0], acc[4+i][ni], 0, 0, 0);
          acc[4+i][ni] = __builtin_amdgcn_mfma_f32_16x16x32_bf16(
              af[i][1], bfr[ni][1], acc[4+i][ni], 0, 0, 0);
        }
      __builtin_amdgcn_s_setprio(0);
    }
    asm volatile("s_barrier" ::: "memory");  // reads done before buf reuse
  }

  const int cr = lg * 4, cc = l15;
#pragma unroll
  for (int mi = 0; mi < 7; ++mi)
#pragma unroll
    for (int j = 0; j < 4; ++j) {
      const int row = m0 + wm * 112 + mi * 16 + cr + j;  // < 8288 <= M_PAD
#pragma unroll
      for (int ni = 0; ni < 4; ++ni) {
        const int col = n0 + wn * 64 + ni * 16 + cc;
        C[(size_t)row * 1536 + col] = f2bf(acc[mi][ni][j]);
      }
    }
}

// --------------------- 160x128 dbuf GEMM (output, one-round grid) ---------
// 208 blocks, single-round makespan. Separate attn_fin kernel retained:
// R6/R8/R13/R14 all showed folding the dense merge anywhere else loses 3-7us.
__global__ __launch_bounds__(256, 1) void gemm160(
    const u16* __restrict__ A, const u16* __restrict__ B,
    float* __restrict__ Cf) {
  __shared__ __align__(16) u16 SM[36864];
  const int tid  = threadIdx.x;
  const int lane = tid & 63;
  const int wid  = tid >> 6;      // 0..3
  const int wm   = wid >> 1, wn = wid & 1;

  const int obid = blockIdx.x;            // 0..207, 208 % 8 == 0
  const int wgid = (obid & 7) * 26 + (obid >> 3);
  const int m0 = (wgid >> 2) * 160;
  const int n0 = (wgid & 3) * 128;

  const int l15 = lane & 15, l7 = lane & 7, lg = lane >> 4;

  const u16* AgP[5];
#pragma unroll
  for (int i = 0; i < 5; ++i) {
    const int s = tid + 256 * i;
    const int row = s >> 3, g = s & 7;
    AgP[i] = A + (size_t)(m0 + row) * KDIM + ((g ^ (row & 7)) << 3);
  }
  const u16* BgP[4];
#pragma unroll
  for (int i = 0; i < 4; ++i) {
    const int s = tid + 256 * i;
    const int row = s >> 3, g = s & 7;
    BgP[i] = B + (size_t)(n0 + row) * KDIM + ((g ^ (row & 7)) << 3);
  }

  const int kx0 = ((lg * 8)       ^ (l7 << 3));
  const int kx1 = (((4 | lg) * 8) ^ (l7 << 3));
  const int aBase = wm * 5120 + l15 * 64;
  const int bBase = 20480 + wn * 4096 + l15 * 64;

  f32x4 acc[5][4] = {};
  constexpr int NT = KDIM / 64;   // 8

  auto stage = [&](int t, int buf) {
#pragma unroll
    for (int i = 0; i < 5; ++i)
      gload_lds16(AgP[i] + t * 64,
                  (char*)SM + buf * 20480 + (tid + 256 * i) * 16);
#pragma unroll
    for (int i = 0; i < 4; ++i)
      gload_lds16(BgP[i] + t * 64,
                  (char*)SM + 40960 + buf * 16384 + (tid + 256 * i) * 16);
  };

  stage(0, 0);

  for (int t = 0; t < NT; ++t) {
    const int buf = t & 1;
    if (t + 1 < NT) {
      stage(t + 1, buf ^ 1);
      asm volatile("s_waitcnt vmcnt(9)" ::: "memory");
    } else {
      asm volatile("s_waitcnt vmcnt(0)" ::: "memory");
    }
    asm volatile("s_barrier" ::: "memory");

    const int aB = aBase + buf * 10240;
    const int bB = bBase + buf * 8192;

    bf16x8 bfr[4][2];
#pragma unroll
    for (int ni = 0; ni < 4; ++ni) {
      bfr[ni][0] = *(const bf16x8*)&SM[bB + ni * 1024 + kx0];
      bfr[ni][1] = *(const bf16x8*)&SM[bB + ni * 1024 + kx1];
    }
    bf16x8 af[5][2];
#pragma unroll
    for (int i = 0; i < 5; ++i) {
      af[i][0] = *(const bf16x8*)&SM[aB + i * 1024 + kx0];
      af[i][1] = *(const bf16x8*)&SM[aB + i * 1024 + kx1];
    }
    __builtin_amdgcn_s_setprio(1);
#pragma unroll
    for (int i = 0; i < 5; ++i)
#pragma unroll
      for (int ni = 0; ni < 4; ++ni) {
        acc[i][ni] = __builtin_amdgcn_mfma_f32_16x16x32_bf16(
            af[i][0], bfr[ni][0], acc[i][ni], 0, 0, 0);
        acc[i][ni] = __builtin_amdgcn_mfma_f32_16x16x32_bf16(
            af[i][1], bfr[ni][1], acc[i][ni], 0, 0, 0);
      }
    __builtin_amdgcn_s_setprio(0);
    asm volatile("s_barrier" ::: "memory");
  }

  const int cr = lg * 4, cc = l15;
#pragma unroll
  for (int mi = 0; mi < 5; ++mi)
#pragma unroll
    for (int j = 0; j < 4; ++j) {
      const int row = m0 + wm * 80 + mi * 16 + cr + j;
      if (row >= M_REAL) continue;
#pragma unroll
      for (int ni = 0; ni < 4; ++ni) {
        const int col = n0 + wn * 64 + ni * 16 + cc;
        Cf[(size_t)row * 512 + col] = acc[mi][ni][j];
      }
    }
}

// ------------------------------------------------------------ attention ----
// blocks [0,NDB): dense-row phase A; [NDB,..): sparse rows, XCD-chunked.
__global__ __launch_bounds__(256) void attn(const u16* __restrict__ QKV,
                                            u16* __restrict__ O,
                                            float* __restrict__ Part) {
  const int tid = threadIdx.x;
  if (blockIdx.x < NDB) {
    __shared__ float qs[64];
    __shared__ float ev[JC];
    __shared__ float red[256];
    const int db = blockIdx.x;
    const int b  = db / (8 * NCHUNK);
    const int rm = db % (8 * NCHUNK);
    const int h  = rm / NCHUNK;
    const int ch = rm % NCHUNK;
    const int j0 = ch * JC;
    const size_t base = (size_t)b * NNODE;

    if (tid < 64) qs[tid] = bf2f(QKV[base * 1536 + h * 64 + tid]);
    __syncthreads();

    const int j = j0 + tid;
    float s = -3e38f;
    if (j < NNODE) {
      const uint4* kp4 = (const uint4*)(QKV + (base + j) * 1536 + 512 + h * 64);
      float a = 0.f;
#pragma unroll
      for (int q8 = 0; q8 < 8; ++q8) {
        uint4 kv = kp4[q8];
        int d = q8 * 8;
        a += qs[d+0]*bflo(kv.x) + qs[d+1]*bfhi(kv.x)
           + qs[d+2]*bflo(kv.y) + qs[d+3]*bfhi(kv.y)
           + qs[d+4]*bflo(kv.z) + qs[d+5]*bfhi(kv.z)
           + qs[d+6]*bflo(kv.w) + qs[d+7]*bfhi(kv.w);
      }
      s = a * 0.125f;
    }
    red[tid] = s;
    __syncthreads();
    for (int st = 128; st > 0; st >>= 1) {
      if (tid < st) red[tid] = fmaxf(red[tid], red[tid + st]);
      __syncthreads();
    }
    const float mx = red[0];
    __syncthreads();
    const float e = (j < NNODE) ? __expf(s - mx) : 0.f;
    ev[tid] = e;
    red[tid] = e;
    __syncthreads();
    for (int st = 128; st > 0; st >>= 1) {
      if (tid < st) red[tid] += red[tid + st];
      __syncthreads();
    }
    const float ssum = red[0];
    __syncthreads();

    const int w = tid >> 6, lane = tid & 63;
    const int js = lane >> 3, dg = lane & 7;
    float oa[8] = {};
#pragma unroll
    for (int jj = 0; jj < 8; ++jj) {
      const int li = w * 64 + jj * 8 + js;
      const int jv = j0 + li;
      if (jv < NNODE) {
        const float we = ev[li];
        const uint4 vv = *(const uint4*)(QKV + (base + jv) * 1536 + 1024 + h * 64 + dg * 8);
        oa[0] += we * bflo(vv.x); oa[1] += we * bfhi(vv.x);
        oa[2] += we * bflo(vv.y); oa[3] += we * bfhi(vv.y);
        oa[4] += we * bflo(vv.z); oa[5] += we * bfhi(vv.z);
        oa[6] += we * bflo(vv.w); oa[7] += we * bfhi(vv.w);
      }
    }
#pragma unroll
    for (int m = 8; m <= 32; m <<= 1)
#pragma unroll
      for (int t = 0; t < 8; ++t) oa[t] += __shfl_xor(oa[t], m);
    __syncthreads();
    if (lane < 8) {
#pragma unroll
      for (int t = 0; t < 8; ++t) red[w * 64 + lane * 8 + t] = oa[t];
    }
    __syncthreads();
    float* P = Part + ((size_t)((b * 8 + h) * NCHUNK + ch)) * 66;
    if (tid == 0) { P[0] = mx; P[1] = ssum; }
    if (tid < 64)
      P[2 + tid] = red[tid] + red[64 + tid] + red[128 + tid] + red[192 + tid];
    return;
  }

  // ---- sparse rows ----
  const int obid = blockIdx.x - NDB;                    // 0..2047
  const int sb   = ((obid & 7) << 8) | (obid >> 3);     // bijective (2048 % 8 == 0)
  const int wid  = sb * 4 + (tid >> 6);                 // 0..8191
  const int lane = tid & 63;
  const int b = wid >> 12;
  const int g = wid & 4095;
  const int i = g + 1;
  const int r = g >> 6, c = g & 63;
  const size_t base = (size_t)b * NNODE;

  int  jn[6];
  bool vd[6];
  jn[0] = 0;                     vd[0] = true;
  jn[1] = i;                     vd[1] = true;
  jn[2] = (c > 0)  ? i - 1  : i; vd[2] = (c > 0);
  jn[3] = (c < 63) ? i + 1  : i; vd[3] = (c < 63);
  jn[4] = (r > 0)  ? i - 64 : i; vd[4] = (r > 0);
  jn[5] = (r < 63) ? i + 64 : i; vd[5] = (r < 63);

  const uint4 qv = *(const uint4*)(QKV + (base + i) * 1536 + lane * 8);
  float qf[8] = { bflo(qv.x), bfhi(qv.x), bflo(qv.y), bfhi(qv.y),
                  bflo(qv.z), bfhi(qv.z), bflo(qv.w), bfhi(qv.w) };

  float sc[6];
#pragma unroll
  for (int n = 0; n < 6; ++n) {
    const uint4 kv = *(const uint4*)(QKV + (base + jn[n]) * 1536 + 512 + lane * 8);
    float p = qf[0]*bflo(kv.x) + qf[1]*bfhi(kv.x)
            + qf[2]*bflo(kv.y) + qf[3]*bfhi(kv.y)
            + qf[4]*bflo(kv.z) + qf[5]*bfhi(kv.z)
            + qf[6]*bflo(kv.w) + qf[7]*bfhi(kv.w);
    p += __shfl_xor(p, 1);
    p += __shfl_xor(p, 2);
    p += __shfl_xor(p, 4);
    sc[n] = p * 0.125f;
  }
  float mx = -1e30f;
#pragma unroll
  for (int n = 0; n < 6; ++n) if (vd[n]) mx = fmaxf(mx, sc[n]);
  float pw[6], den = 0.f;
#pragma unroll
  for (int n = 0; n < 6; ++n) {
    pw[n] = vd[n] ? __expf(sc[n] - mx) : 0.f;
    den += pw[n];
  }
  const float inv = 1.f / den;

  float oa[8] = {};
#pragma unroll
  for (int n = 0; n < 6; ++n) {
    const uint4 vv = *(const uint4*)(QKV + (base + jn[n]) * 1536 + 1024 + lane * 8);
    const float w = pw[n];
    oa[0] += w * bflo(vv.x); oa[1] += w * bfhi(vv.x);
    oa[2] += w * bflo(vv.y); oa[3] += w * bfhi(vv.y);
    oa[4] += w * bflo(vv.z); oa[5] += w * bfhi(vv.z);
    oa[6] += w * bflo(vv.w); oa[7] += w * bfhi(vv.w);
  }
  uint4 ov;
  ov.x = (u32)f2bf(oa[0] * inv) | ((u32)f2bf(oa[1] * inv) << 16);
  ov.y = (u32)f2bf(oa[2] * inv) | ((u32)f2bf(oa[3] * inv) << 16);
  ov.z = (u32)f2bf(oa[4] * inv) | ((u32)f2bf(oa[5] * inv) << 16);
  ov.w = (u32)f2bf(oa[6] * inv) | ((u32)f2bf(oa[7] * inv) << 16);
  *(uint4*)(O + (base + i) * 512 + lane * 8) = ov;
}

// phase B: merge the NCHUNK partials per (b,h), write O row 0 (16 parallel blocks).
__global__ __launch_bounds__(64) void attn_fin(const float* __restrict__ Part,
                                               u16* __restrict__ O) {
  const int b = blockIdx.x >> 3, h = blockIdx.x & 7;
  const int d = threadIdx.x;
  const float* P = Part + ((size_t)(b * 8 + h) * NCHUNK) * 66;
  float m = -3e38f;
  for (int c = 0; c < NCHUNK; ++c) m = fmaxf(m, P[c * 66]);
  float s = 0.f, o = 0.f;
  for (int c = 0; c < NCHUNK; ++c) {
    const float ex = __expf(P[c * 66] - m);
    s += P[c * 66 + 1] * ex;
    o += P[c * 66 + 2 + d] * ex;
  }
  O[(size_t)b * NNODE * 512 + h * 64 + d] = f2bf(o / s);
}

// -------------------------------------------------------------- launch ----
extern "C" void kernel_launch(void* const* d_in, const int* in_sizes, int n_in,
                              void* d_out, int out_size, void* d_ws, size_t ws_size,
                              hipStream_t stream) {
  (void)in_sizes; (void)n_in; (void)out_size; (void)ws_size;
  const float* x  = (const float*)d_in[0];
  const float* wq = (const float*)d_in[1];
  const float* wk = (const float*)d_in[2];
  const float* wv = (const float*)d_in[3];
  const float* wo = (const float*)d_in[4];
  float* out = (float*)d_out;

  char* ws = (char*)d_ws;
  u16* Xp   = (u16*)ws;  ws += (size_t)M_PAD * 512 * 2;   //  8,650,752 B
  u16* Wqkv = (u16*)ws;  ws += (size_t)1536 * 512 * 2;    //  1,572,864 B
  u16* Wob  = (u16*)ws;  ws += (size_t)512 * 512 * 2;     //    524,288 B
  u16* QKV  = (u16*)ws;  ws += (size_t)M_PAD * 1536 * 2;  // 25,952,256 B
  u16* ATT  = (u16*)ws;                                   //  8,650,752 B
  float* Part = (float*)Xp;  // dead after gemm1; 272*66*4 = 72 KB

  prep<<<(NCH_X + NCH_WQ + NCH_WO) / 256, 256, 0, stream>>>(
      x, wq, wk, wv, wo, Xp, Wqkv, Wob);

  gemm224<<<222, 512, 0, stream>>>(Xp, Wqkv, QKV);

  attn<<<NDB + 2048, 256, 0, stream>>>(QKV, ATT, Part);
  attn_fin<<<16, 64, 0, stream>>>(Part, ATT);

  gemm160<<<208, 256, 0, stream>>>(ATT, Wob, out);
}